// Round 6
// baseline (316.259 us; speedup 1.0000x reference)
//
#include <hip/hip_runtime.h>
#include <hip/hip_bf16.h>

// Problem constants (match reference)
#define BATCH   8
#define CDIM    256
#define ODIM    16
#define GRID16  16
#define NCELL   4096            // 16*16*16
#define PADW    17
#define PADV    (PADW*PADW*PADW)
#define MAXK    32              // point chunks per batch (256 blocks total)
#define SENT16  0x007Fu         // mapped bf16 -inf
#define SENTPK  0x007F007Fu

// ws layout (u32 words):
//   [0, 1024)      : W1b1 packed float4 per c  (w1,w1,w1,b1)
//   [1024, 3072)   : W2 bf16 MFMA B-fragments, uint4 per (kt*64+lane)
//                    k-map: c = kt*32 + j*4 + g   (j = k-slot pair idx, g = lane>>4)
//   [4096, ...)    : Km * BATCH slabs of 4096*8 packed-bf16-pair u32
//                    word index = cell*8 + op   (op = channel pair 0..7)
#define HDR_WORDS   4096
#define SLAB_WORDS  (8 * 4096)   // 32768 u32 = 128 KiB

typedef __attribute__((ext_vector_type(8))) short bf16x8;
typedef __attribute__((ext_vector_type(4))) float f32x4;
typedef __attribute__((ext_vector_type(4))) unsigned u32x4;

// ---------------------------------------------------------------------------
// monotone bf16(u16) <-> mapped-u16 so unsigned max == float max
__device__ __forceinline__ unsigned map16(unsigned r) {
    return (r ^ ((r & 0x8000u) ? 0xFFFFu : 0x8000u)) & 0xFFFFu;
}
__device__ __forceinline__ float unmap16(unsigned m) {
    unsigned r = (m & 0x8000u) ? (m ^ 0x8000u) : (~m & 0xFFFFu);
    return __uint_as_float(r << 16);
}
// fp32 -> bf16 bits, RTNE (matches __float2bfloat16_rn for normals)
__device__ __forceinline__ unsigned bf16rtne(float v) {
    unsigned u = __float_as_uint(v);
    return (u + 0x7FFFu + ((u >> 16) & 1u)) >> 16;
}
// two fp32 -> packed bf16 pair (lo = first), pure integer, register-only
__device__ __forceinline__ unsigned pkbf16(float lo, float hi) {
    return bf16rtne(lo) | (bf16rtne(hi) << 16);
}
// packed-pair unsigned max per 16-bit field
__device__ __forceinline__ unsigned pmax(unsigned a, unsigned b) {
    unsigned hi = max(a >> 16, b >> 16);
    unsigned lo = max(a & 0xFFFFu, b & 0xFFFFu);
    return (hi << 16) | lo;
}

// ---------------------------------------------------------------------------
__global__ void k_pack2(const float* __restrict__ W1, const float* __restrict__ b1,
                        const float* __restrict__ W2, unsigned* __restrict__ ws) {
    int t = threadIdx.x;                    // 512 threads
    float* w1p = reinterpret_cast<float*>(ws);
    if (t < 256) {
        float4 v;
        v.x = W1[t * 3 + 0];
        v.y = W1[t * 3 + 1];
        v.z = W1[t * 3 + 2];
        v.w = b1[t];
        reinterpret_cast<float4*>(w1p)[t] = v;
    }
    // B fragments, k-map c = kt*32 + j*4 + g:
    // uint4 word i packs (c = base+8i, c = base+8i+4), base = kt*32 + g
    int kt = t >> 6, l = t & 63;
    int g = (l >> 4), o = l & 15;
    const float* wr = W2 + o * CDIM + kt * 32 + g;
    uint4 q;
    q.x = pkbf16(wr[0],  wr[4]);
    q.y = pkbf16(wr[8],  wr[12]);
    q.z = pkbf16(wr[16], wr[20]);
    q.w = pkbf16(wr[24], wr[28]);
    reinterpret_cast<uint4*>(ws + 1024)[t] = q;
}

// ---------------------------------------------------------------------------
// per-word (2x bf16-mapped u16) max via CAS; low contention expected
__device__ __forceinline__ void casmax(unsigned* addr, unsigned wv) {
    unsigned cur = *addr;
    while (true) {
        unsigned nv = pmax(cur, wv);
        if (nv == cur) return;
        unsigned prev = atomicCAS(addr, cur, nv);
        if (prev == cur) return;
        cur = prev;
    }
}

// ---------------------------------------------------------------------------
// MFMA scatter: block (k, b). 16 waves; each wave does 2x 16-point M-tiles
// per iteration. LDS grid cell-major: cm[cell*8 + op] (op = channel pair).
// W2 fragments live in LDS (8 KiB), re-read per kt -> low VGPR pressure.
__global__ __launch_bounds__(1024)
void k_scatter_mfma(const float* __restrict__ xin,
                    const unsigned* __restrict__ ws,
                    const float* __restrict__ b2,
                    unsigned* __restrict__ slabs,
                    int nper, int chunk) {
    __shared__ unsigned cm[SLAB_WORDS];      // 128 KiB
    __shared__ float4 w1s[256];              // 4 KiB
    __shared__ u32x4 w2s[512];               // 8 KiB
    const int kblk = blockIdx.x, b = blockIdx.z;
    const int tid = threadIdx.x;
    const int l = tid & 63, wv = tid >> 6;   // lane, wave
    const int g = l >> 4;                    // lane group 0..3

    if (tid < 256)
        w1s[tid] = reinterpret_cast<const float4*>(ws)[tid];
    if (tid < 512)
        w2s[tid] = reinterpret_cast<const u32x4*>(ws + 1024)[tid];
    {   // vectorized sentinel init: 8192 uint4
        u32x4 s = {SENTPK, SENTPK, SENTPK, SENTPK};
        u32x4* cm4 = reinterpret_cast<u32x4*>(cm);
        for (int i = tid; i < SLAB_WORDS / 4; i += 1024) cm4[i] = s;
    }
    float b2v = b2[l & 15];
    __syncthreads();

    const int p0 = kblk * chunk;
    const int p1 = min(p0 + chunk, nper);
    const float* xb = xin + (size_t)b * nper * 3;

    for (int gb = p0 + wv * 32; gb < p1; gb += 16 * 32) {
        // ---- load x for 2 tiles (16 pts each) ----
        int pa = min(gb + (l & 15), nper - 1);
        int pb = min(gb + 16 + (l & 15), nper - 1);
        float ax = xb[pa * 3 + 0], ay = xb[pa * 3 + 1], az = xb[pa * 3 + 2];
        float bx = xb[pb * 3 + 0], by = xb[pb * 3 + 1], bz = xb[pb * 3 + 2];
        int cellA = ((min(max((int)floorf(ax), 0), 15) << 8) |
                     (min(max((int)floorf(ay), 0), 15) << 4) |
                      min(max((int)floorf(az), 0), 15));
        int cellB = ((min(max((int)floorf(bx), 0), 15) << 8) |
                     (min(max((int)floorf(by), 0), 15) << 4) |
                      min(max((int)floorf(bz), 0), 15));

        f32x4 accA = {0.f, 0.f, 0.f, 0.f};
        f32x4 accB = {0.f, 0.f, 0.f, 0.f};
#pragma unroll
        for (int kt = 0; kt < 8; ++kt) {
            const int cbase = kt * 32 + g;   // c = cbase + 8i (+4)
            u32x4 uaV, ubV;
#pragma unroll
            for (int i = 0; i < 4; ++i) {
                float4 w0 = w1s[cbase + 8 * i];
                float4 w1 = w1s[cbase + 8 * i + 4];
                float hA0 = fmaxf(fmaf(w0.x, ax, fmaf(w0.y, ay, fmaf(w0.z, az, w0.w))), 0.f);
                float hA1 = fmaxf(fmaf(w1.x, ax, fmaf(w1.y, ay, fmaf(w1.z, az, w1.w))), 0.f);
                float hB0 = fmaxf(fmaf(w0.x, bx, fmaf(w0.y, by, fmaf(w0.z, bz, w0.w))), 0.f);
                float hB1 = fmaxf(fmaf(w1.x, bx, fmaf(w1.y, by, fmaf(w1.z, bz, w1.w))), 0.f);
                uaV[i] = pkbf16(hA0, hA1);
                ubV[i] = pkbf16(hB0, hB1);
            }
            u32x4 wq = w2s[kt * 64 + l];     // ds_read_b128, contiguous
            bf16x8 wf = __builtin_bit_cast(bf16x8, wq);
            accA = __builtin_amdgcn_mfma_f32_16x16x32_bf16(
                       __builtin_bit_cast(bf16x8, uaV), wf, accA, 0, 0, 0);
            accB = __builtin_amdgcn_mfma_f32_16x16x32_bf16(
                       __builtin_bit_cast(bf16x8, ubV), wf, accB, 0, 0, 0);
        }

        // ---- epilogue per tile: +b2, bf16-map, pack pairs, CAS into cm ----
#pragma unroll
        for (int tile = 0; tile < 2; ++tile) {
            f32x4 acc = tile ? accB : accA;
            int cell16 = tile ? cellB : cellA;
            int gbase = gb + tile * 16;

            unsigned m0 = map16(bf16rtne(acc[0] + b2v));
            unsigned m1 = map16(bf16rtne(acc[1] + b2v));
            unsigned m2 = map16(bf16rtne(acc[2] + b2v));
            unsigned m3 = map16(bf16rtne(acc[3] + b2v));

            unsigned pk01 = m0 | (m1 << 16);
            unsigned pk23 = m2 | (m3 << 16);
            unsigned q01 = __shfl_xor(pk01, 1);
            unsigned q23 = __shfl_xor(pk23, 1);
            int half = l & 1;
            unsigned aown = half ? pk23 : pk01;
            unsigned apar = half ? q23 : q01;
            unsigned losrc = half ? apar : aown;   // even channel -> lo
            unsigned hisrc = half ? aown : apar;   // odd channel  -> hi
            unsigned wA = (losrc & 0xFFFFu) | ((hisrc & 0xFFFFu) << 16);
            unsigned wB = (losrc >> 16) | (hisrc & 0xFFFF0000u);
            int r0 = g * 4 + half * 2;
            int cA = __shfl(cell16, r0);
            int cB = __shfl(cell16, r0 + 1);
            unsigned op = (l >> 1) & 7;
            if (gbase + r0 < p1)     casmax(&cm[cA * 8 + op], wA);
            if (gbase + r0 + 1 < p1) casmax(&cm[cB * 8 + op], wB);
        }
    }
    __syncthreads();

    // flush slab (flat copy; layout preserved)
    unsigned* dst = slabs + (size_t)(kblk * BATCH + b) * SLAB_WORDS;
    uint4* d4 = reinterpret_cast<uint4*>(dst);
    const uint4* s4 = reinterpret_cast<const uint4*>(cm);
    for (int i = tid; i < SLAB_WORDS / 4; i += 1024) d4[i] = s4[i];
}

// ---------------------------------------------------------------------------
// reduce K slabs -> out interior. thread = (b, cell); reads 8 contiguous
// words per slab (2x uint4), writes 16 channels.
__global__ __launch_bounds__(256)
void k_reduce3(const unsigned* __restrict__ slabs, float* __restrict__ out, int K) {
    int t = blockIdx.x * 256 + threadIdx.x;
    if (t >= BATCH * NCELL) return;
    int cell = t & (NCELL - 1), b = t >> 12;

    unsigned m[8];
#pragma unroll
    for (int i = 0; i < 8; ++i) m[i] = SENTPK;

    for (int k = 0; k < K; ++k) {
        const uint4* s = reinterpret_cast<const uint4*>(
            slabs + (size_t)(k * BATCH + b) * SLAB_WORDS + (size_t)cell * 8);
        uint4 a = s[0], c = s[1];
        m[0] = pmax(m[0], a.x); m[1] = pmax(m[1], a.y);
        m[2] = pmax(m[2], a.z); m[3] = pmax(m[3], a.w);
        m[4] = pmax(m[4], c.x); m[5] = pmax(m[5], c.y);
        m[6] = pmax(m[6], c.z); m[7] = pmax(m[7], c.w);
    }

    int ix = cell >> 8, iy = (cell >> 4) & 15, iz = cell & 15;
    size_t obase = ((size_t)b * ODIM) * PADV + ((ix * PADW + iy) * PADW + iz);
#pragma unroll
    for (int op = 0; op < 8; ++op) {
        unsigned lo = m[op] & 0xFFFFu, hi = m[op] >> 16;
        out[obase + (size_t)(2 * op)     * PADV] = (lo == SENT16) ? 0.0f : unmap16(lo);
        out[obase + (size_t)(2 * op + 1) * PADV] = (hi == SENT16) ? 0.0f : unmap16(hi);
    }
}

// ===========================================================================
// Fallback (round-1): direct global atomics. Used only if ws too small.
__global__ void k_init(unsigned* __restrict__ out, int total) {
    int i = blockIdx.x * blockDim.x + threadIdx.x;
    if (i >= total) return;
    int r = i % PADV;
    int z = r % PADW, y = (r / PADW) % PADW, x = r / (PADW * PADW);
    out[i] = (x < GRID16 && y < GRID16 && z < GRID16) ? 0xFF800000u : 0u;
}
__device__ __forceinline__ void atomicMaxFloat(float* addr, float v) {
    if (v >= 0.0f) atomicMax(reinterpret_cast<int*>(addr), __float_as_int(v));
    else           atomicMin(reinterpret_cast<unsigned*>(addr), __float_as_uint(v));
}
__global__ __launch_bounds__(256)
void k_scatter_glb(const float* __restrict__ xin,
                   const float* __restrict__ W1, const float* __restrict__ b1,
                   const float* __restrict__ W2, const float* __restrict__ b2,
                   float* __restrict__ out, int npts, int nper) {
    int p = blockIdx.x * 256 + threadIdx.x;
    if (p >= npts) return;
    float x0 = xin[p*3+0], x1 = xin[p*3+1], x2 = xin[p*3+2];
    float acc[ODIM];
#pragma unroll
    for (int o = 0; o < ODIM; ++o) acc[o] = b2[o];
#pragma unroll 2
    for (int c = 0; c < CDIM; ++c) {
        float h = fmaf(W1[c*3+0], x0, fmaf(W1[c*3+1], x1, fmaf(W1[c*3+2], x2, b1[c])));
        h = fmaxf(h, 0.0f);
#pragma unroll
        for (int o = 0; o < ODIM; ++o) acc[o] = fmaf(W2[o*CDIM+c], h, acc[o]);
    }
    int ix = min(max((int)floorf(x0), 0), GRID16-1);
    int iy = min(max((int)floorf(x1), 0), GRID16-1);
    int iz = min(max((int)floorf(x2), 0), GRID16-1);
    int b = p / nper;
    size_t base = ((((size_t)b*ODIM)*PADW + ix)*PADW + iy)*PADW + iz;
#pragma unroll
    for (int o = 0; o < ODIM; ++o)
        atomicMaxFloat(out + base + (size_t)o*PADV, acc[o]);
}
__global__ void k_final(unsigned* __restrict__ out, int total) {
    int i = blockIdx.x * blockDim.x + threadIdx.x;
    if (i >= total) return;
    if (out[i] == 0xFF800000u) out[i] = 0u;
}

// ===========================================================================
extern "C" void kernel_launch(void* const* d_in, const int* in_sizes, int n_in,
                              void* d_out, int out_size, void* d_ws, size_t ws_size,
                              hipStream_t stream) {
    const float* x  = (const float*)d_in[0];
    const float* W1 = (const float*)d_in[1];
    const float* b1 = (const float*)d_in[2];
    const float* W2 = (const float*)d_in[3];
    const float* b2 = (const float*)d_in[4];
    float* out = (float*)d_out;

    int npts = in_sizes[0] / 3;          // B*N
    int nper = npts / BATCH;             // N

    size_t ws_words = ws_size / 4;
    int Km = 0;
    if (ws_words > HDR_WORDS) {
        size_t avail = (ws_words - HDR_WORDS) / ((size_t)BATCH * SLAB_WORDS);
        Km = (int)min((size_t)MAXK, avail);
    }

    if (Km >= 1) {
        unsigned* ws = (unsigned*)d_ws;
        k_pack2<<<1, 512, 0, stream>>>(W1, b1, W2, ws);
        (void)hipMemsetAsync(d_out, 0, (size_t)out_size * sizeof(float), stream);

        unsigned* slabs = ws + HDR_WORDS;
        int chunk = (nper + Km - 1) / Km;
        dim3 grid(Km, 1, BATCH);
        k_scatter_mfma<<<grid, 1024, 0, stream>>>(x, ws, b2, slabs, nper, chunk);

        int rt = BATCH * NCELL;
        k_reduce3<<<(rt + 255) / 256, 256, 0, stream>>>(slabs, out, Km);
    } else {
        int total = out_size;
        k_init<<<(total + 255) / 256, 256, 0, stream>>>((unsigned*)out, total);
        int blocks = (npts + 255) / 256;
        k_scatter_glb<<<blocks, 256, 0, stream>>>(x, W1, b1, W2, b2, out, npts, nper);
        k_final<<<(total + 255) / 256, 256, 0, stream>>>((unsigned*)out, total);
    }
}

// Round 7
// 177.559 us; speedup vs baseline: 1.7812x; 1.7812x over previous
//
#include <hip/hip_runtime.h>
#include <hip/hip_bf16.h>

// Problem constants (match reference)
#define BATCH   8
#define CDIM    256
#define ODIM    16
#define GRID16  16
#define NCELL   4096            // 16*16*16
#define PADW    17
#define PADV    (PADW*PADW*PADW)
#define MAXK    32              // point chunks per batch (256 blocks total)
#define SENT16  0x007Fu         // mapped bf16 -inf
#define SENTPK  0x007F007Fu
#define TPB     512             // 8 waves: 2/SIMD -> 256-reg budget, no spill

// ws layout (u32 words):
//   [0, 1024)      : W1b1 packed float4 per c  (w1,w1,w1,b1)
//   [1024, 3072)   : W2 bf16 MFMA B-fragments, uint4 per (kt*64+lane)
//                    k-map: c = kt*32 + j*4 + g   (j = k-slot pair idx, g = lane>>4)
//   [4096, ...)    : Km * BATCH slabs of 4096*8 packed-bf16-pair u32
//                    word index = cell*8 + op   (op = channel pair 0..7)
#define HDR_WORDS   4096
#define SLAB_WORDS  (8 * 4096)   // 32768 u32 = 128 KiB

typedef __attribute__((ext_vector_type(8))) short bf16x8;
typedef __attribute__((ext_vector_type(4))) float f32x4;
typedef __attribute__((ext_vector_type(4))) unsigned u32x4;

// ---------------------------------------------------------------------------
// monotone bf16(u16) <-> mapped-u16 so unsigned max == float max
__device__ __forceinline__ unsigned map16(unsigned r) {
    return (r ^ ((r & 0x8000u) ? 0xFFFFu : 0x8000u)) & 0xFFFFu;
}
__device__ __forceinline__ float unmap16(unsigned m) {
    unsigned r = (m & 0x8000u) ? (m ^ 0x8000u) : (~m & 0xFFFFu);
    return __uint_as_float(r << 16);
}
// fp32 -> bf16 bits, RTNE (matches __float2bfloat16_rn for normals)
__device__ __forceinline__ unsigned bf16rtne(float v) {
    unsigned u = __float_as_uint(v);
    return (u + 0x7FFFu + ((u >> 16) & 1u)) >> 16;
}
// two fp32 -> packed bf16 pair (lo = first), pure integer, register-only
__device__ __forceinline__ unsigned pkbf16(float lo, float hi) {
    return bf16rtne(lo) | (bf16rtne(hi) << 16);
}
// packed-pair unsigned max per 16-bit field
__device__ __forceinline__ unsigned pmax(unsigned a, unsigned b) {
    unsigned hi = max(a >> 16, b >> 16);
    unsigned lo = max(a & 0xFFFFu, b & 0xFFFFu);
    return (hi << 16) | lo;
}

// ---------------------------------------------------------------------------
__global__ void k_pack2(const float* __restrict__ W1, const float* __restrict__ b1,
                        const float* __restrict__ W2, unsigned* __restrict__ ws) {
    int t = threadIdx.x;                    // 512 threads
    float* w1p = reinterpret_cast<float*>(ws);
    if (t < 256) {
        float4 v;
        v.x = W1[t * 3 + 0];
        v.y = W1[t * 3 + 1];
        v.z = W1[t * 3 + 2];
        v.w = b1[t];
        reinterpret_cast<float4*>(w1p)[t] = v;
    }
    // B fragments, k-map c = kt*32 + j*4 + g:
    // uint4 word i packs (c = base+8i, c = base+8i+4), base = kt*32 + g
    int kt = t >> 6, l = t & 63;
    int g = (l >> 4), o = l & 15;
    const float* wr = W2 + o * CDIM + kt * 32 + g;
    uint4 q;
    q.x = pkbf16(wr[0],  wr[4]);
    q.y = pkbf16(wr[8],  wr[12]);
    q.z = pkbf16(wr[16], wr[20]);
    q.w = pkbf16(wr[24], wr[28]);
    reinterpret_cast<uint4*>(ws + 1024)[t] = q;
}

// ---------------------------------------------------------------------------
// per-word (2x bf16-mapped u16) max via CAS; low contention expected
__device__ __forceinline__ void casmax(unsigned* addr, unsigned wv) {
    unsigned cur = *addr;
    while (true) {
        unsigned nv = pmax(cur, wv);
        if (nv == cur) return;
        unsigned prev = atomicCAS(addr, cur, nv);
        if (prev == cur) return;
        cur = prev;
    }
}

// ---------------------------------------------------------------------------
// MFMA scatter: block (k, b). 8 waves; each wave does 2x 16-point M-tiles
// per iteration. LDS grid cell-major: cm[cell*8 + op] (op = channel pair).
// TPB=512: 2 waves/SIMD residency -> 256-reg/wave budget (vs 128 at 1024TPB
// which forced the 64-arch-VGPR spill seen in R3/R5/R6).
__global__ __launch_bounds__(TPB, 2)
void k_scatter_mfma(const float* __restrict__ xin,
                    const unsigned* __restrict__ ws,
                    const float* __restrict__ b2,
                    unsigned* __restrict__ slabs,
                    int nper, int chunk) {
    __shared__ unsigned cm[SLAB_WORDS];      // 128 KiB
    __shared__ float4 w1s[256];              // 4 KiB
    __shared__ u32x4 w2s[512];               // 8 KiB
    const int kblk = blockIdx.x, b = blockIdx.z;
    const int tid = threadIdx.x;
    const int l = tid & 63, wv = tid >> 6;   // lane, wave (0..7)
    const int g = l >> 4;                    // lane group 0..3

    if (tid < 256)
        w1s[tid] = reinterpret_cast<const float4*>(ws)[tid];
    w2s[tid] = reinterpret_cast<const u32x4*>(ws + 1024)[tid];
    {   // vectorized sentinel init: 8192 uint4
        u32x4 s = {SENTPK, SENTPK, SENTPK, SENTPK};
        u32x4* cm4 = reinterpret_cast<u32x4*>(cm);
        for (int i = tid; i < SLAB_WORDS / 4; i += TPB) cm4[i] = s;
    }
    float b2v = b2[l & 15];
    __syncthreads();

    const int p0 = kblk * chunk;
    const int p1 = min(p0 + chunk, nper);
    const float* xb = xin + (size_t)b * nper * 3;

    for (int gb = p0 + wv * 32; gb < p1; gb += (TPB / 64) * 32) {
        // ---- load x for 2 tiles (16 pts each) ----
        int pa = min(gb + (l & 15), nper - 1);
        int pb = min(gb + 16 + (l & 15), nper - 1);
        float ax = xb[pa * 3 + 0], ay = xb[pa * 3 + 1], az = xb[pa * 3 + 2];
        float bx = xb[pb * 3 + 0], by = xb[pb * 3 + 1], bz = xb[pb * 3 + 2];
        int cellA = ((min(max((int)floorf(ax), 0), 15) << 8) |
                     (min(max((int)floorf(ay), 0), 15) << 4) |
                      min(max((int)floorf(az), 0), 15));
        int cellB = ((min(max((int)floorf(bx), 0), 15) << 8) |
                     (min(max((int)floorf(by), 0), 15) << 4) |
                      min(max((int)floorf(bz), 0), 15));

        f32x4 accA = {0.f, 0.f, 0.f, 0.f};
        f32x4 accB = {0.f, 0.f, 0.f, 0.f};
#pragma unroll
        for (int kt = 0; kt < 8; ++kt) {
            const int cbase = kt * 32 + g;   // c = cbase + 8i (+4)
            u32x4 uaV, ubV;
#pragma unroll
            for (int i = 0; i < 4; ++i) {
                float4 w0 = w1s[cbase + 8 * i];
                float4 w1 = w1s[cbase + 8 * i + 4];
                float hA0 = fmaxf(fmaf(w0.x, ax, fmaf(w0.y, ay, fmaf(w0.z, az, w0.w))), 0.f);
                float hA1 = fmaxf(fmaf(w1.x, ax, fmaf(w1.y, ay, fmaf(w1.z, az, w1.w))), 0.f);
                float hB0 = fmaxf(fmaf(w0.x, bx, fmaf(w0.y, by, fmaf(w0.z, bz, w0.w))), 0.f);
                float hB1 = fmaxf(fmaf(w1.x, bx, fmaf(w1.y, by, fmaf(w1.z, bz, w1.w))), 0.f);
                uaV[i] = pkbf16(hA0, hA1);
                ubV[i] = pkbf16(hB0, hB1);
            }
            u32x4 wq = w2s[kt * 64 + l];     // ds_read_b128, contiguous
            bf16x8 wf = __builtin_bit_cast(bf16x8, wq);
            accA = __builtin_amdgcn_mfma_f32_16x16x32_bf16(
                       __builtin_bit_cast(bf16x8, uaV), wf, accA, 0, 0, 0);
            accB = __builtin_amdgcn_mfma_f32_16x16x32_bf16(
                       __builtin_bit_cast(bf16x8, ubV), wf, accB, 0, 0, 0);
        }

        // ---- epilogue per tile: +b2, bf16-map, pack pairs, CAS into cm ----
#pragma unroll
        for (int tile = 0; tile < 2; ++tile) {
            f32x4 acc = tile ? accB : accA;
            int cell16 = tile ? cellB : cellA;
            int gbase = gb + tile * 16;

            unsigned m0 = map16(bf16rtne(acc[0] + b2v));
            unsigned m1 = map16(bf16rtne(acc[1] + b2v));
            unsigned m2 = map16(bf16rtne(acc[2] + b2v));
            unsigned m3 = map16(bf16rtne(acc[3] + b2v));

            unsigned pk01 = m0 | (m1 << 16);
            unsigned pk23 = m2 | (m3 << 16);
            unsigned q01 = __shfl_xor(pk01, 1);
            unsigned q23 = __shfl_xor(pk23, 1);
            int half = l & 1;
            unsigned aown = half ? pk23 : pk01;
            unsigned apar = half ? q23 : q01;
            unsigned losrc = half ? apar : aown;   // even channel -> lo
            unsigned hisrc = half ? aown : apar;   // odd channel  -> hi
            unsigned wA = (losrc & 0xFFFFu) | ((hisrc & 0xFFFFu) << 16);
            unsigned wB = (losrc >> 16) | (hisrc & 0xFFFF0000u);
            int r0 = g * 4 + half * 2;
            int cA = __shfl(cell16, r0);
            int cB = __shfl(cell16, r0 + 1);
            unsigned op = (l >> 1) & 7;
            if (gbase + r0 < p1)     casmax(&cm[cA * 8 + op], wA);
            if (gbase + r0 + 1 < p1) casmax(&cm[cB * 8 + op], wB);
        }
    }
    __syncthreads();

    // flush slab (flat copy; layout preserved)
    unsigned* dst = slabs + (size_t)(kblk * BATCH + b) * SLAB_WORDS;
    uint4* d4 = reinterpret_cast<uint4*>(dst);
    const uint4* s4 = reinterpret_cast<const uint4*>(cm);
    for (int i = tid; i < SLAB_WORDS / 4; i += TPB) d4[i] = s4[i];
}

// ---------------------------------------------------------------------------
// reduce K slabs -> out interior. thread = (b, cell); reads 8 contiguous
// words per slab (2x uint4), writes 16 channels.
__global__ __launch_bounds__(256)
void k_reduce3(const unsigned* __restrict__ slabs, float* __restrict__ out, int K) {
    int t = blockIdx.x * 256 + threadIdx.x;
    if (t >= BATCH * NCELL) return;
    int cell = t & (NCELL - 1), b = t >> 12;

    unsigned m[8];
#pragma unroll
    for (int i = 0; i < 8; ++i) m[i] = SENTPK;

    for (int k = 0; k < K; ++k) {
        const uint4* s = reinterpret_cast<const uint4*>(
            slabs + (size_t)(k * BATCH + b) * SLAB_WORDS + (size_t)cell * 8);
        uint4 a = s[0], c = s[1];
        m[0] = pmax(m[0], a.x); m[1] = pmax(m[1], a.y);
        m[2] = pmax(m[2], a.z); m[3] = pmax(m[3], a.w);
        m[4] = pmax(m[4], c.x); m[5] = pmax(m[5], c.y);
        m[6] = pmax(m[6], c.z); m[7] = pmax(m[7], c.w);
    }

    int ix = cell >> 8, iy = (cell >> 4) & 15, iz = cell & 15;
    size_t obase = ((size_t)b * ODIM) * PADV + ((ix * PADW + iy) * PADW + iz);
#pragma unroll
    for (int op = 0; op < 8; ++op) {
        unsigned lo = m[op] & 0xFFFFu, hi = m[op] >> 16;
        out[obase + (size_t)(2 * op)     * PADV] = (lo == SENT16) ? 0.0f : unmap16(lo);
        out[obase + (size_t)(2 * op + 1) * PADV] = (hi == SENT16) ? 0.0f : unmap16(hi);
    }
}

// ===========================================================================
// Fallback (round-1): direct global atomics. Used only if ws too small.
__global__ void k_init(unsigned* __restrict__ out, int total) {
    int i = blockIdx.x * blockDim.x + threadIdx.x;
    if (i >= total) return;
    int r = i % PADV;
    int z = r % PADW, y = (r / PADW) % PADW, x = r / (PADW * PADW);
    out[i] = (x < GRID16 && y < GRID16 && z < GRID16) ? 0xFF800000u : 0u;
}
__device__ __forceinline__ void atomicMaxFloat(float* addr, float v) {
    if (v >= 0.0f) atomicMax(reinterpret_cast<int*>(addr), __float_as_int(v));
    else           atomicMin(reinterpret_cast<unsigned*>(addr), __float_as_uint(v));
}
__global__ __launch_bounds__(256)
void k_scatter_glb(const float* __restrict__ xin,
                   const float* __restrict__ W1, const float* __restrict__ b1,
                   const float* __restrict__ W2, const float* __restrict__ b2,
                   float* __restrict__ out, int npts, int nper) {
    int p = blockIdx.x * 256 + threadIdx.x;
    if (p >= npts) return;
    float x0 = xin[p*3+0], x1 = xin[p*3+1], x2 = xin[p*3+2];
    float acc[ODIM];
#pragma unroll
    for (int o = 0; o < ODIM; ++o) acc[o] = b2[o];
#pragma unroll 2
    for (int c = 0; c < CDIM; ++c) {
        float h = fmaf(W1[c*3+0], x0, fmaf(W1[c*3+1], x1, fmaf(W1[c*3+2], x2, b1[c])));
        h = fmaxf(h, 0.0f);
#pragma unroll
        for (int o = 0; o < ODIM; ++o) acc[o] = fmaf(W2[o*CDIM+c], h, acc[o]);
    }
    int ix = min(max((int)floorf(x0), 0), GRID16-1);
    int iy = min(max((int)floorf(x1), 0), GRID16-1);
    int iz = min(max((int)floorf(x2), 0), GRID16-1);
    int b = p / nper;
    size_t base = ((((size_t)b*ODIM)*PADW + ix)*PADW + iy)*PADW + iz;
#pragma unroll
    for (int o = 0; o < ODIM; ++o)
        atomicMaxFloat(out + base + (size_t)o*PADV, acc[o]);
}
__global__ void k_final(unsigned* __restrict__ out, int total) {
    int i = blockIdx.x * blockDim.x + threadIdx.x;
    if (i >= total) return;
    if (out[i] == 0xFF800000u) out[i] = 0u;
}

// ===========================================================================
extern "C" void kernel_launch(void* const* d_in, const int* in_sizes, int n_in,
                              void* d_out, int out_size, void* d_ws, size_t ws_size,
                              hipStream_t stream) {
    const float* x  = (const float*)d_in[0];
    const float* W1 = (const float*)d_in[1];
    const float* b1 = (const float*)d_in[2];
    const float* W2 = (const float*)d_in[3];
    const float* b2 = (const float*)d_in[4];
    float* out = (float*)d_out;

    int npts = in_sizes[0] / 3;          // B*N
    int nper = npts / BATCH;             // N

    size_t ws_words = ws_size / 4;
    int Km = 0;
    if (ws_words > HDR_WORDS) {
        size_t avail = (ws_words - HDR_WORDS) / ((size_t)BATCH * SLAB_WORDS);
        Km = (int)min((size_t)MAXK, avail);
    }

    if (Km >= 1) {
        unsigned* ws = (unsigned*)d_ws;
        k_pack2<<<1, 512, 0, stream>>>(W1, b1, W2, ws);
        (void)hipMemsetAsync(d_out, 0, (size_t)out_size * sizeof(float), stream);

        unsigned* slabs = ws + HDR_WORDS;
        int chunk = (nper + Km - 1) / Km;
        dim3 grid(Km, 1, BATCH);
        k_scatter_mfma<<<grid, TPB, 0, stream>>>(x, ws, b2, slabs, nper, chunk);

        int rt = BATCH * NCELL;
        k_reduce3<<<(rt + 255) / 256, 256, 0, stream>>>(slabs, out, Km);
    } else {
        int total = out_size;
        k_init<<<(total + 255) / 256, 256, 0, stream>>>((unsigned*)out, total);
        int blocks = (npts + 255) / 256;
        k_scatter_glb<<<blocks, 256, 0, stream>>>(x, W1, b1, W2, b2, out, npts, nper);
        k_final<<<(total + 255) / 256, 256, 0, stream>>>((unsigned*)out, total);
    }
}

// Round 8
// 110.427 us; speedup vs baseline: 2.8640x; 1.6079x over previous
//
#include <hip/hip_runtime.h>
#include <hip/hip_bf16.h>

// Problem constants (match reference)
#define BATCH   8
#define CDIM    256
#define ODIM    16
#define GRID16  16
#define NCELL   4096            // 16*16*16
#define PADW    17
#define PADV    (PADW*PADW*PADW)
#define MAXK    32              // point chunks per batch (256 blocks total)
#define SENT16  0x007Fu         // mapped bf16 -inf
#define SENTPK  0x007F007Fu
#define TPB     256             // 4 waves: 1/SIMD -> 512-reg budget, no spill

// ws layout (u32 words):
//   [0, 1024)      : W1b1 packed float4 per c  (w1,w1,w1,b1)
//   [1024, 3072)   : W2 bf16 MFMA B-fragments, uint4 per (kt*64+lane)
//                    k-map: c = kt*32 + j*4 + g   (j = k-slot pair idx, g = lane>>4)
//   [4096, ...)    : Km * BATCH slabs of 4096*8 packed-bf16-pair u32
//                    word index = cell*8 + op   (op = channel pair 0..7)
#define HDR_WORDS   4096
#define SLAB_WORDS  (8 * 4096)   // 32768 u32 = 128 KiB

typedef __attribute__((ext_vector_type(8))) short bf16x8;
typedef __attribute__((ext_vector_type(4))) float f32x4;
typedef __attribute__((ext_vector_type(4))) unsigned u32x4;

// ---------------------------------------------------------------------------
// monotone bf16(u16) <-> mapped-u16 so unsigned max == float max
__device__ __forceinline__ unsigned map16(unsigned r) {
    return (r ^ ((r & 0x8000u) ? 0xFFFFu : 0x8000u)) & 0xFFFFu;
}
__device__ __forceinline__ float unmap16(unsigned m) {
    unsigned r = (m & 0x8000u) ? (m ^ 0x8000u) : (~m & 0xFFFFu);
    return __uint_as_float(r << 16);
}
// fp32 -> bf16 bits, RTNE (matches __float2bfloat16_rn for normals)
__device__ __forceinline__ unsigned bf16rtne(float v) {
    unsigned u = __float_as_uint(v);
    return (u + 0x7FFFu + ((u >> 16) & 1u)) >> 16;
}
// two fp32 -> packed bf16 pair (lo = first), pure integer, register-only
__device__ __forceinline__ unsigned pkbf16(float lo, float hi) {
    return bf16rtne(lo) | (bf16rtne(hi) << 16);
}
// packed-pair unsigned max per 16-bit field
__device__ __forceinline__ unsigned pmax(unsigned a, unsigned b) {
    unsigned hi = max(a >> 16, b >> 16);
    unsigned lo = max(a & 0xFFFFu, b & 0xFFFFu);
    return (hi << 16) | lo;
}

// ---------------------------------------------------------------------------
__global__ void k_pack2(const float* __restrict__ W1, const float* __restrict__ b1,
                        const float* __restrict__ W2, unsigned* __restrict__ ws) {
    int t = threadIdx.x;                    // 512 threads
    float* w1p = reinterpret_cast<float*>(ws);
    if (t < 256) {
        float4 v;
        v.x = W1[t * 3 + 0];
        v.y = W1[t * 3 + 1];
        v.z = W1[t * 3 + 2];
        v.w = b1[t];
        reinterpret_cast<float4*>(w1p)[t] = v;
    }
    // B fragments, k-map c = kt*32 + j*4 + g:
    // uint4 word i packs (c = base+8i, c = base+8i+4), base = kt*32 + g
    int kt = t >> 6, l = t & 63;
    int g = (l >> 4), o = l & 15;
    const float* wr = W2 + o * CDIM + kt * 32 + g;
    uint4 q;
    q.x = pkbf16(wr[0],  wr[4]);
    q.y = pkbf16(wr[8],  wr[12]);
    q.z = pkbf16(wr[16], wr[20]);
    q.w = pkbf16(wr[24], wr[28]);
    reinterpret_cast<uint4*>(ws + 1024)[t] = q;
}

// ---------------------------------------------------------------------------
// per-word (2x bf16-mapped u16) max via CAS; low contention expected
__device__ __forceinline__ void casmax(unsigned* addr, unsigned wv) {
    unsigned cur = *addr;
    while (true) {
        unsigned nv = pmax(cur, wv);
        if (nv == cur) return;
        unsigned prev = atomicCAS(addr, cur, nv);
        if (prev == cur) return;
        cur = prev;
    }
}

// ---------------------------------------------------------------------------
// MFMA scatter: block (k, b). 4 waves; each wave does 2x 16-point M-tiles
// per iteration. LDS grid cell-major: cm[cell*8 + op] (op = channel pair).
// TPB=256 + min 1 wave/EU: 512-reg unified budget -> the ~200-reg live set
// (full kt-unroll pipeline) fits without the spill seen at 64/128-reg caps.
__global__ __launch_bounds__(TPB, 1)
void k_scatter_mfma(const float* __restrict__ xin,
                    const unsigned* __restrict__ ws,
                    const float* __restrict__ b2,
                    unsigned* __restrict__ slabs,
                    int nper, int chunk) {
    __shared__ unsigned cm[SLAB_WORDS];      // 128 KiB
    __shared__ float4 w1s[256];              // 4 KiB
    __shared__ u32x4 w2s[512];               // 8 KiB
    const int kblk = blockIdx.x, b = blockIdx.z;
    const int tid = threadIdx.x;
    const int l = tid & 63, wv = tid >> 6;   // lane, wave (0..3)
    const int g = l >> 4;                    // lane group 0..3

    w1s[tid] = reinterpret_cast<const float4*>(ws)[tid];
    w2s[tid] = reinterpret_cast<const u32x4*>(ws + 1024)[tid];
    w2s[tid + 256] = reinterpret_cast<const u32x4*>(ws + 1024)[tid + 256];
    {   // vectorized sentinel init: 8192 uint4
        u32x4 s = {SENTPK, SENTPK, SENTPK, SENTPK};
        u32x4* cm4 = reinterpret_cast<u32x4*>(cm);
        for (int i = tid; i < SLAB_WORDS / 4; i += TPB) cm4[i] = s;
    }
    float b2v = b2[l & 15];
    __syncthreads();

    const int p0 = kblk * chunk;
    const int p1 = min(p0 + chunk, nper);
    const float* xb = xin + (size_t)b * nper * 3;

    for (int gb = p0 + wv * 32; gb < p1; gb += (TPB / 64) * 32) {
        // ---- load x for 2 tiles (16 pts each) ----
        int pa = min(gb + (l & 15), nper - 1);
        int pb = min(gb + 16 + (l & 15), nper - 1);
        float ax = xb[pa * 3 + 0], ay = xb[pa * 3 + 1], az = xb[pa * 3 + 2];
        float bx = xb[pb * 3 + 0], by = xb[pb * 3 + 1], bz = xb[pb * 3 + 2];
        int cellA = ((min(max((int)floorf(ax), 0), 15) << 8) |
                     (min(max((int)floorf(ay), 0), 15) << 4) |
                      min(max((int)floorf(az), 0), 15));
        int cellB = ((min(max((int)floorf(bx), 0), 15) << 8) |
                     (min(max((int)floorf(by), 0), 15) << 4) |
                      min(max((int)floorf(bz), 0), 15));

        f32x4 accA = {0.f, 0.f, 0.f, 0.f};
        f32x4 accB = {0.f, 0.f, 0.f, 0.f};
#pragma unroll
        for (int kt = 0; kt < 8; ++kt) {
            const int cbase = kt * 32 + g;   // c = cbase + 8i (+4)
            u32x4 uaV, ubV;
#pragma unroll
            for (int i = 0; i < 4; ++i) {
                float4 w0 = w1s[cbase + 8 * i];
                float4 w1 = w1s[cbase + 8 * i + 4];
                float hA0 = fmaxf(fmaf(w0.x, ax, fmaf(w0.y, ay, fmaf(w0.z, az, w0.w))), 0.f);
                float hA1 = fmaxf(fmaf(w1.x, ax, fmaf(w1.y, ay, fmaf(w1.z, az, w1.w))), 0.f);
                float hB0 = fmaxf(fmaf(w0.x, bx, fmaf(w0.y, by, fmaf(w0.z, bz, w0.w))), 0.f);
                float hB1 = fmaxf(fmaf(w1.x, bx, fmaf(w1.y, by, fmaf(w1.z, bz, w1.w))), 0.f);
                uaV[i] = pkbf16(hA0, hA1);
                ubV[i] = pkbf16(hB0, hB1);
            }
            u32x4 wq = w2s[kt * 64 + l];     // ds_read_b128, contiguous
            bf16x8 wf = __builtin_bit_cast(bf16x8, wq);
            accA = __builtin_amdgcn_mfma_f32_16x16x32_bf16(
                       __builtin_bit_cast(bf16x8, uaV), wf, accA, 0, 0, 0);
            accB = __builtin_amdgcn_mfma_f32_16x16x32_bf16(
                       __builtin_bit_cast(bf16x8, ubV), wf, accB, 0, 0, 0);
        }

        // ---- epilogue per tile: +b2, bf16-map, pack pairs, CAS into cm ----
#pragma unroll
        for (int tile = 0; tile < 2; ++tile) {
            f32x4 acc = tile ? accB : accA;
            int cell16 = tile ? cellB : cellA;
            int gbase = gb + tile * 16;

            unsigned m0 = map16(bf16rtne(acc[0] + b2v));
            unsigned m1 = map16(bf16rtne(acc[1] + b2v));
            unsigned m2 = map16(bf16rtne(acc[2] + b2v));
            unsigned m3 = map16(bf16rtne(acc[3] + b2v));

            unsigned pk01 = m0 | (m1 << 16);
            unsigned pk23 = m2 | (m3 << 16);
            unsigned q01 = __shfl_xor(pk01, 1);
            unsigned q23 = __shfl_xor(pk23, 1);
            int half = l & 1;
            unsigned aown = half ? pk23 : pk01;
            unsigned apar = half ? q23 : q01;
            unsigned losrc = half ? apar : aown;   // even channel -> lo
            unsigned hisrc = half ? aown : apar;   // odd channel  -> hi
            unsigned wA = (losrc & 0xFFFFu) | ((hisrc & 0xFFFFu) << 16);
            unsigned wB = (losrc >> 16) | (hisrc & 0xFFFF0000u);
            int r0 = g * 4 + half * 2;
            int cA = __shfl(cell16, r0);
            int cB = __shfl(cell16, r0 + 1);
            unsigned op = (l >> 1) & 7;
            if (gbase + r0 < p1)     casmax(&cm[cA * 8 + op], wA);
            if (gbase + r0 + 1 < p1) casmax(&cm[cB * 8 + op], wB);
        }
    }
    __syncthreads();

    // flush slab (flat copy; layout preserved)
    unsigned* dst = slabs + (size_t)(kblk * BATCH + b) * SLAB_WORDS;
    uint4* d4 = reinterpret_cast<uint4*>(dst);
    const uint4* s4 = reinterpret_cast<const uint4*>(cm);
    for (int i = tid; i < SLAB_WORDS / 4; i += TPB) d4[i] = s4[i];
}

// ---------------------------------------------------------------------------
// reduce K slabs -> out interior. thread = (b, cell); reads 8 contiguous
// words per slab (2x uint4), writes 16 channels.
__global__ __launch_bounds__(256)
void k_reduce3(const unsigned* __restrict__ slabs, float* __restrict__ out, int K) {
    int t = blockIdx.x * 256 + threadIdx.x;
    if (t >= BATCH * NCELL) return;
    int cell = t & (NCELL - 1), b = t >> 12;

    unsigned m[8];
#pragma unroll
    for (int i = 0; i < 8; ++i) m[i] = SENTPK;

    for (int k = 0; k < K; ++k) {
        const uint4* s = reinterpret_cast<const uint4*>(
            slabs + (size_t)(k * BATCH + b) * SLAB_WORDS + (size_t)cell * 8);
        uint4 a = s[0], c = s[1];
        m[0] = pmax(m[0], a.x); m[1] = pmax(m[1], a.y);
        m[2] = pmax(m[2], a.z); m[3] = pmax(m[3], a.w);
        m[4] = pmax(m[4], c.x); m[5] = pmax(m[5], c.y);
        m[6] = pmax(m[6], c.z); m[7] = pmax(m[7], c.w);
    }

    int ix = cell >> 8, iy = (cell >> 4) & 15, iz = cell & 15;
    size_t obase = ((size_t)b * ODIM) * PADV + ((ix * PADW + iy) * PADW + iz);
#pragma unroll
    for (int op = 0; op < 8; ++op) {
        unsigned lo = m[op] & 0xFFFFu, hi = m[op] >> 16;
        out[obase + (size_t)(2 * op)     * PADV] = (lo == SENT16) ? 0.0f : unmap16(lo);
        out[obase + (size_t)(2 * op + 1) * PADV] = (hi == SENT16) ? 0.0f : unmap16(hi);
    }
}

// ===========================================================================
// Fallback (round-1): direct global atomics. Used only if ws too small.
__global__ void k_init(unsigned* __restrict__ out, int total) {
    int i = blockIdx.x * blockDim.x + threadIdx.x;
    if (i >= total) return;
    int r = i % PADV;
    int z = r % PADW, y = (r / PADW) % PADW, x = r / (PADW * PADW);
    out[i] = (x < GRID16 && y < GRID16 && z < GRID16) ? 0xFF800000u : 0u;
}
__device__ __forceinline__ void atomicMaxFloat(float* addr, float v) {
    if (v >= 0.0f) atomicMax(reinterpret_cast<int*>(addr), __float_as_int(v));
    else           atomicMin(reinterpret_cast<unsigned*>(addr), __float_as_uint(v));
}
__global__ __launch_bounds__(256)
void k_scatter_glb(const float* __restrict__ xin,
                   const float* __restrict__ W1, const float* __restrict__ b1,
                   const float* __restrict__ W2, const float* __restrict__ b2,
                   float* __restrict__ out, int npts, int nper) {
    int p = blockIdx.x * 256 + threadIdx.x;
    if (p >= npts) return;
    float x0 = xin[p*3+0], x1 = xin[p*3+1], x2 = xin[p*3+2];
    float acc[ODIM];
#pragma unroll
    for (int o = 0; o < ODIM; ++o) acc[o] = b2[o];
#pragma unroll 2
    for (int c = 0; c < CDIM; ++c) {
        float h = fmaf(W1[c*3+0], x0, fmaf(W1[c*3+1], x1, fmaf(W1[c*3+2], x2, b1[c])));
        h = fmaxf(h, 0.0f);
#pragma unroll
        for (int o = 0; o < ODIM; ++o) acc[o] = fmaf(W2[o*CDIM+c], h, acc[o]);
    }
    int ix = min(max((int)floorf(x0), 0), GRID16-1);
    int iy = min(max((int)floorf(x1), 0), GRID16-1);
    int iz = min(max((int)floorf(x2), 0), GRID16-1);
    int b = p / nper;
    size_t base = ((((size_t)b*ODIM)*PADW + ix)*PADW + iy)*PADW + iz;
#pragma unroll
    for (int o = 0; o < ODIM; ++o)
        atomicMaxFloat(out + base + (size_t)o*PADV, acc[o]);
}
__global__ void k_final(unsigned* __restrict__ out, int total) {
    int i = blockIdx.x * blockDim.x + threadIdx.x;
    if (i >= total) return;
    if (out[i] == 0xFF800000u) out[i] = 0u;
}

// ===========================================================================
extern "C" void kernel_launch(void* const* d_in, const int* in_sizes, int n_in,
                              void* d_out, int out_size, void* d_ws, size_t ws_size,
                              hipStream_t stream) {
    const float* x  = (const float*)d_in[0];
    const float* W1 = (const float*)d_in[1];
    const float* b1 = (const float*)d_in[2];
    const float* W2 = (const float*)d_in[3];
    const float* b2 = (const float*)d_in[4];
    float* out = (float*)d_out;

    int npts = in_sizes[0] / 3;          // B*N
    int nper = npts / BATCH;             // N

    size_t ws_words = ws_size / 4;
    int Km = 0;
    if (ws_words > HDR_WORDS) {
        size_t avail = (ws_words - HDR_WORDS) / ((size_t)BATCH * SLAB_WORDS);
        Km = (int)min((size_t)MAXK, avail);
    }

    if (Km >= 1) {
        unsigned* ws = (unsigned*)d_ws;
        k_pack2<<<1, 512, 0, stream>>>(W1, b1, W2, ws);
        (void)hipMemsetAsync(d_out, 0, (size_t)out_size * sizeof(float), stream);

        unsigned* slabs = ws + HDR_WORDS;
        int chunk = (nper + Km - 1) / Km;
        dim3 grid(Km, 1, BATCH);
        k_scatter_mfma<<<grid, TPB, 0, stream>>>(x, ws, b2, slabs, nper, chunk);

        int rt = BATCH * NCELL;
        k_reduce3<<<(rt + 255) / 256, 256, 0, stream>>>(slabs, out, Km);
    } else {
        int total = out_size;
        k_init<<<(total + 255) / 256, 256, 0, stream>>>((unsigned*)out, total);
        int blocks = (npts + 255) / 256;
        k_scatter_glb<<<blocks, 256, 0, stream>>>(x, W1, b1, W2, b2, out, npts, nper);
        k_final<<<(total + 255) / 256, 256, 0, stream>>>((unsigned*)out, total);
    }
}

// Round 9
// 77.214 us; speedup vs baseline: 4.0959x; 1.4301x over previous
//
#include <hip/hip_runtime.h>
#include <hip/hip_bf16.h>

// Problem constants (match reference)
#define BATCH   8
#define CDIM    256
#define ODIM    16
#define GRID16  16
#define NCELL   4096            // 16*16*16
#define PADW    17
#define PADV    (PADW*PADW*PADW)
#define MAXK    32              // point chunks per batch (256 blocks total)
#define SENT16  0x007Fu         // mapped bf16 -inf
#define SENTPK  0x007F007Fu
#define TPB     512             // 8 waves = 2/SIMD; bounds(512,1) -> 256-reg cap

// ws layout (u32 words):
//   [0, 1024)      : W1b1 packed float4 per c  (w1,w1,w1,b1)
//   [1024, 3072)   : W2 bf16 MFMA B-fragments, uint4 per (kt*64+lane)
//                    k-map: c = kt*32 + j*4 + g   (j = k-slot pair idx, g = lane>>4)
//   [4096, ...)    : Km * BATCH slabs of 4096*8 packed-bf16-pair u32
//                    word index = cell*8 + op   (op = channel pair 0..7)
#define HDR_WORDS   4096
#define SLAB_WORDS  (8 * 4096)   // 32768 u32 = 128 KiB

typedef __attribute__((ext_vector_type(8))) short bf16x8;
typedef __attribute__((ext_vector_type(4))) float f32x4;
typedef __attribute__((ext_vector_type(4))) unsigned u32x4;

// ---------------------------------------------------------------------------
// monotone bf16(u16) <-> mapped-u16 so unsigned max == float max
__device__ __forceinline__ float unmap16(unsigned m) {
    unsigned r = (m & 0x8000u) ? (m ^ 0x8000u) : (~m & 0xFFFFu);
    return __uint_as_float(r << 16);
}
// packed pair map: per 16-bit field, r ^= (sign ? 0xFFFF : 0x8000)
__device__ __forceinline__ unsigned mpk(unsigned w) {
    return w ^ (0x80008000u | (((w >> 15) & 0x00010001u) * 0x7FFFu));
}
// two fp32 -> packed bf16 pair (lo = first): single HW instruction (T12)
__device__ __forceinline__ unsigned pkbf16(float lo, float hi) {
    unsigned r;
    asm("v_cvt_pk_bf16_f32 %0, %1, %2" : "=v"(r) : "v"(lo), "v"(hi));
    return r;
}
// packed-pair unsigned max per 16-bit field
__device__ __forceinline__ unsigned pmax(unsigned a, unsigned b) {
    unsigned hi = max(a >> 16, b >> 16);
    unsigned lo = max(a & 0xFFFFu, b & 0xFFFFu);
    return (hi << 16) | lo;
}

// ---------------------------------------------------------------------------
__global__ void k_pack2(const float* __restrict__ W1, const float* __restrict__ b1,
                        const float* __restrict__ W2, unsigned* __restrict__ ws) {
    int t = threadIdx.x;                    // 512 threads
    float* w1p = reinterpret_cast<float*>(ws);
    if (t < 256) {
        float4 v;
        v.x = W1[t * 3 + 0];
        v.y = W1[t * 3 + 1];
        v.z = W1[t * 3 + 2];
        v.w = b1[t];
        reinterpret_cast<float4*>(w1p)[t] = v;
    }
    // B fragments, k-map c = kt*32 + j*4 + g:
    // uint4 word i packs (c = base+8i, c = base+8i+4), base = kt*32 + g
    int kt = t >> 6, l = t & 63;
    int g = (l >> 4), o = l & 15;
    const float* wr = W2 + o * CDIM + kt * 32 + g;
    uint4 q;
    q.x = pkbf16(wr[0],  wr[4]);
    q.y = pkbf16(wr[8],  wr[12]);
    q.z = pkbf16(wr[16], wr[20]);
    q.w = pkbf16(wr[24], wr[28]);
    reinterpret_cast<uint4*>(ws + 1024)[t] = q;
}

// ---------------------------------------------------------------------------
// per-word (2x bf16-mapped u16) max via CAS; low contention expected
__device__ __forceinline__ void casmax(unsigned* addr, unsigned wv) {
    unsigned cur = *addr;
    while (true) {
        unsigned nv = pmax(cur, wv);
        if (nv == cur) return;
        unsigned prev = atomicCAS(addr, cur, nv);
        if (prev == cur) return;
        cur = prev;
    }
}

// ---------------------------------------------------------------------------
// MFMA scatter: block (k, b). 8 waves (2/SIMD); each wave does 2x 16-point
// M-tiles per iteration. LDS grid cell-major: cm[cell*8 + op].
// launch_bounds(512,1): 256-reg cap; live set ~180 -> no spill (R8 lesson:
// the *declared* min-waves sets the cap; 1024TPB/[512,2] forced 64/128-reg
// spill regimes).
__global__ __launch_bounds__(TPB, 1)
void k_scatter_mfma(const float* __restrict__ xin,
                    const unsigned* __restrict__ ws,
                    const float* __restrict__ b2,
                    unsigned* __restrict__ slabs,
                    int nper, int chunk) {
    __shared__ unsigned cm[SLAB_WORDS];      // 128 KiB
    __shared__ float4 w1s[256];              // 4 KiB
    __shared__ u32x4 w2s[512];               // 8 KiB
    const int kblk = blockIdx.x, b = blockIdx.z;
    const int tid = threadIdx.x;
    const int l = tid & 63, wv = tid >> 6;   // lane, wave (0..7)
    const int g = l >> 4;                    // lane group 0..3

    if (tid < 256)
        w1s[tid] = reinterpret_cast<const float4*>(ws)[tid];
    w2s[tid] = reinterpret_cast<const u32x4*>(ws + 1024)[tid];
    {   // vectorized sentinel init: 8192 uint4
        u32x4 s = {SENTPK, SENTPK, SENTPK, SENTPK};
        u32x4* cm4 = reinterpret_cast<u32x4*>(cm);
        for (int i = tid; i < SLAB_WORDS / 4; i += TPB) cm4[i] = s;
    }
    float b2v = b2[l & 15];
    __syncthreads();

    const int p0 = kblk * chunk;
    const int p1 = min(p0 + chunk, nper);
    const float* xb = xin + (size_t)b * nper * 3;

    for (int gb = p0 + wv * 32; gb < p1; gb += (TPB / 64) * 32) {
        // ---- load x for 2 tiles (16 pts each) ----
        int pa = min(gb + (l & 15), nper - 1);
        int pb = min(gb + 16 + (l & 15), nper - 1);
        float ax = xb[pa * 3 + 0], ay = xb[pa * 3 + 1], az = xb[pa * 3 + 2];
        float bx = xb[pb * 3 + 0], by = xb[pb * 3 + 1], bz = xb[pb * 3 + 2];
        int cellA = ((min(max((int)floorf(ax), 0), 15) << 8) |
                     (min(max((int)floorf(ay), 0), 15) << 4) |
                      min(max((int)floorf(az), 0), 15));
        int cellB = ((min(max((int)floorf(bx), 0), 15) << 8) |
                     (min(max((int)floorf(by), 0), 15) << 4) |
                      min(max((int)floorf(bz), 0), 15));

        f32x4 accA = {0.f, 0.f, 0.f, 0.f};
        f32x4 accB = {0.f, 0.f, 0.f, 0.f};
#pragma unroll
        for (int kt = 0; kt < 8; ++kt) {
            const int cbase = kt * 32 + g;   // c = cbase + 8i (+4)
            u32x4 uaV, ubV;
#pragma unroll
            for (int i = 0; i < 4; ++i) {
                float4 w0 = w1s[cbase + 8 * i];
                float4 w1 = w1s[cbase + 8 * i + 4];
                float hA0 = fmaxf(fmaf(w0.x, ax, fmaf(w0.y, ay, fmaf(w0.z, az, w0.w))), 0.f);
                float hA1 = fmaxf(fmaf(w1.x, ax, fmaf(w1.y, ay, fmaf(w1.z, az, w1.w))), 0.f);
                float hB0 = fmaxf(fmaf(w0.x, bx, fmaf(w0.y, by, fmaf(w0.z, bz, w0.w))), 0.f);
                float hB1 = fmaxf(fmaf(w1.x, bx, fmaf(w1.y, by, fmaf(w1.z, bz, w1.w))), 0.f);
                uaV[i] = pkbf16(hA0, hA1);
                ubV[i] = pkbf16(hB0, hB1);
            }
            u32x4 wq = w2s[kt * 64 + l];     // ds_read_b128, contiguous
            bf16x8 wf = __builtin_bit_cast(bf16x8, wq);
            accA = __builtin_amdgcn_mfma_f32_16x16x32_bf16(
                       __builtin_bit_cast(bf16x8, uaV), wf, accA, 0, 0, 0);
            accB = __builtin_amdgcn_mfma_f32_16x16x32_bf16(
                       __builtin_bit_cast(bf16x8, ubV), wf, accB, 0, 0, 0);
        }

        // ---- epilogue per tile: +b2, bf16 cvt_pk, packed map, CAS into cm --
#pragma unroll
        for (int tile = 0; tile < 2; ++tile) {
            f32x4 acc = tile ? accB : accA;
            int cell16 = tile ? cellB : cellA;
            int gbase = gb + tile * 16;

            unsigned pk01 = mpk(pkbf16(acc[0] + b2v, acc[1] + b2v));
            unsigned pk23 = mpk(pkbf16(acc[2] + b2v, acc[3] + b2v));
            unsigned q01 = __shfl_xor(pk01, 1);
            unsigned q23 = __shfl_xor(pk23, 1);
            int half = l & 1;
            unsigned aown = half ? pk23 : pk01;
            unsigned apar = half ? q23 : q01;
            unsigned losrc = half ? apar : aown;   // even channel -> lo
            unsigned hisrc = half ? aown : apar;   // odd channel  -> hi
            unsigned wA = (losrc & 0xFFFFu) | ((hisrc & 0xFFFFu) << 16);
            unsigned wB = (losrc >> 16) | (hisrc & 0xFFFF0000u);
            int r0 = g * 4 + half * 2;
            int cA = __shfl(cell16, r0);
            int cB = __shfl(cell16, r0 + 1);
            unsigned op = (l >> 1) & 7;
            if (gbase + r0 < p1)     casmax(&cm[cA * 8 + op], wA);
            if (gbase + r0 + 1 < p1) casmax(&cm[cB * 8 + op], wB);
        }
    }
    __syncthreads();

    // flush slab (flat copy; layout preserved)
    unsigned* dst = slabs + (size_t)(kblk * BATCH + b) * SLAB_WORDS;
    uint4* d4 = reinterpret_cast<uint4*>(dst);
    const uint4* s4 = reinterpret_cast<const uint4*>(cm);
    for (int i = tid; i < SLAB_WORDS / 4; i += TPB) d4[i] = s4[i];
}

// ---------------------------------------------------------------------------
// reduce K slabs -> out interior. thread = (b, cell); reads 8 contiguous
// words per slab (2x uint4), writes 16 channels.
__global__ __launch_bounds__(256)
void k_reduce3(const unsigned* __restrict__ slabs, float* __restrict__ out, int K) {
    int t = blockIdx.x * 256 + threadIdx.x;
    if (t >= BATCH * NCELL) return;
    int cell = t & (NCELL - 1), b = t >> 12;

    unsigned m[8];
#pragma unroll
    for (int i = 0; i < 8; ++i) m[i] = SENTPK;

    for (int k = 0; k < K; ++k) {
        const uint4* s = reinterpret_cast<const uint4*>(
            slabs + (size_t)(k * BATCH + b) * SLAB_WORDS + (size_t)cell * 8);
        uint4 a = s[0], c = s[1];
        m[0] = pmax(m[0], a.x); m[1] = pmax(m[1], a.y);
        m[2] = pmax(m[2], a.z); m[3] = pmax(m[3], a.w);
        m[4] = pmax(m[4], c.x); m[5] = pmax(m[5], c.y);
        m[6] = pmax(m[6], c.z); m[7] = pmax(m[7], c.w);
    }

    int ix = cell >> 8, iy = (cell >> 4) & 15, iz = cell & 15;
    size_t obase = ((size_t)b * ODIM) * PADV + ((ix * PADW + iy) * PADW + iz);
#pragma unroll
    for (int op = 0; op < 8; ++op) {
        unsigned lo = m[op] & 0xFFFFu, hi = m[op] >> 16;
        out[obase + (size_t)(2 * op)     * PADV] = (lo == SENT16) ? 0.0f : unmap16(lo);
        out[obase + (size_t)(2 * op + 1) * PADV] = (hi == SENT16) ? 0.0f : unmap16(hi);
    }
}

// ===========================================================================
// Fallback (round-1): direct global atomics. Used only if ws too small.
__global__ void k_init(unsigned* __restrict__ out, int total) {
    int i = blockIdx.x * blockDim.x + threadIdx.x;
    if (i >= total) return;
    int r = i % PADV;
    int z = r % PADW, y = (r / PADW) % PADW, x = r / (PADW * PADW);
    out[i] = (x < GRID16 && y < GRID16 && z < GRID16) ? 0xFF800000u : 0u;
}
__device__ __forceinline__ void atomicMaxFloat(float* addr, float v) {
    if (v >= 0.0f) atomicMax(reinterpret_cast<int*>(addr), __float_as_int(v));
    else           atomicMin(reinterpret_cast<unsigned*>(addr), __float_as_uint(v));
}
__global__ __launch_bounds__(256)
void k_scatter_glb(const float* __restrict__ xin,
                   const float* __restrict__ W1, const float* __restrict__ b1,
                   const float* __restrict__ W2, const float* __restrict__ b2,
                   float* __restrict__ out, int npts, int nper) {
    int p = blockIdx.x * 256 + threadIdx.x;
    if (p >= npts) return;
    float x0 = xin[p*3+0], x1 = xin[p*3+1], x2 = xin[p*3+2];
    float acc[ODIM];
#pragma unroll
    for (int o = 0; o < ODIM; ++o) acc[o] = b2[o];
#pragma unroll 2
    for (int c = 0; c < CDIM; ++c) {
        float h = fmaf(W1[c*3+0], x0, fmaf(W1[c*3+1], x1, fmaf(W1[c*3+2], x2, b1[c])));
        h = fmaxf(h, 0.0f);
#pragma unroll
        for (int o = 0; o < ODIM; ++o) acc[o] = fmaf(W2[o*CDIM+c], h, acc[o]);
    }
    int ix = min(max((int)floorf(x0), 0), GRID16-1);
    int iy = min(max((int)floorf(x1), 0), GRID16-1);
    int iz = min(max((int)floorf(x2), 0), GRID16-1);
    int b = p / nper;
    size_t base = ((((size_t)b*ODIM)*PADW + ix)*PADW + iy)*PADW + iz;
#pragma unroll
    for (int o = 0; o < ODIM; ++o)
        atomicMaxFloat(out + base + (size_t)o*PADV, acc[o]);
}
__global__ void k_final(unsigned* __restrict__ out, int total) {
    int i = blockIdx.x * blockDim.x + threadIdx.x;
    if (i >= total) return;
    if (out[i] == 0xFF800000u) out[i] = 0u;
}

// ===========================================================================
extern "C" void kernel_launch(void* const* d_in, const int* in_sizes, int n_in,
                              void* d_out, int out_size, void* d_ws, size_t ws_size,
                              hipStream_t stream) {
    const float* x  = (const float*)d_in[0];
    const float* W1 = (const float*)d_in[1];
    const float* b1 = (const float*)d_in[2];
    const float* W2 = (const float*)d_in[3];
    const float* b2 = (const float*)d_in[4];
    float* out = (float*)d_out;

    int npts = in_sizes[0] / 3;          // B*N
    int nper = npts / BATCH;             // N

    size_t ws_words = ws_size / 4;
    int Km = 0;
    if (ws_words > HDR_WORDS) {
        size_t avail = (ws_words - HDR_WORDS) / ((size_t)BATCH * SLAB_WORDS);
        Km = (int)min((size_t)MAXK, avail);
    }

    if (Km >= 1) {
        unsigned* ws = (unsigned*)d_ws;
        k_pack2<<<1, 512, 0, stream>>>(W1, b1, W2, ws);
        (void)hipMemsetAsync(d_out, 0, (size_t)out_size * sizeof(float), stream);

        unsigned* slabs = ws + HDR_WORDS;
        int chunk = (nper + Km - 1) / Km;
        dim3 grid(Km, 1, BATCH);
        k_scatter_mfma<<<grid, TPB, 0, stream>>>(x, ws, b2, slabs, nper, chunk);

        int rt = BATCH * NCELL;
        k_reduce3<<<(rt + 255) / 256, 256, 0, stream>>>(slabs, out, Km);
    } else {
        int total = out_size;
        k_init<<<(total + 255) / 256, 256, 0, stream>>>((unsigned*)out, total);
        int blocks = (npts + 255) / 256;
        k_scatter_glb<<<blocks, 256, 0, stream>>>(x, W1, b1, W2, b2, out, npts, nper);
        k_final<<<(total + 255) / 256, 256, 0, stream>>>((unsigned*)out, total);
    }
}

// Round 10
// 72.159 us; speedup vs baseline: 4.3828x; 1.0701x over previous
//
#include <hip/hip_runtime.h>
#include <hip/hip_bf16.h>

// Problem constants (match reference)
#define BATCH   8
#define CDIM    256
#define ODIM    16
#define GRID16  16
#define NCELL   4096            // 16*16*16
#define PADW    17
#define PADV    (PADW*PADW*PADW)
#define MAXK    32              // point chunks per batch (256 blocks total)
#define SENT16  0x007Fu         // mapped bf16 -inf
#define SENTPK  0x007F007Fu
#define TPB     512             // 8 waves = 2/SIMD; bounds(512,1) -> 256-reg cap

// ws layout (u32 words):
//   [0, 1024)      : W1b1 packed float4 per c  (w1x,w1y,w1z,b1)
//   [1024, 3072)   : W2 bf16 MFMA B-fragments, uint4 per (kt*64+lane)
//                    k-map: c(kt,j,g) = kt*32 + (j>>2)*16 + 4g + (j&3)
//                    (chosen so L1-MFMA output rows land in-lane for L2 A)
//   [4096, ...)    : Km * BATCH slabs of 4096*8 packed-bf16-pair u32
//                    word index = cell*8 + op   (op = channel pair 0..7)
#define HDR_WORDS   4096
#define SLAB_WORDS  (8 * 4096)   // 32768 u32 = 128 KiB

typedef __attribute__((ext_vector_type(8))) short bf16x8;
typedef __attribute__((ext_vector_type(4))) float f32x4;
typedef __attribute__((ext_vector_type(4))) unsigned u32x4;

// ---------------------------------------------------------------------------
// monotone bf16(u16) <-> mapped-u16 so unsigned max == float max
__device__ __forceinline__ float unmap16(unsigned m) {
    unsigned r = (m & 0x8000u) ? (m ^ 0x8000u) : (~m & 0xFFFFu);
    return __uint_as_float(r << 16);
}
// packed pair map: per 16-bit field, r ^= (sign ? 0xFFFF : 0x8000)
__device__ __forceinline__ unsigned mpk(unsigned w) {
    return w ^ (0x80008000u | (((w >> 15) & 0x00010001u) * 0x7FFFu));
}
// two fp32 -> packed bf16 pair (lo = first): single HW instruction (T12)
__device__ __forceinline__ unsigned pkbf16(float lo, float hi) {
    unsigned r;
    asm("v_cvt_pk_bf16_f32 %0, %1, %2" : "=v"(r) : "v"(lo), "v"(hi));
    return r;
}
// packed-pair unsigned max per 16-bit field
__device__ __forceinline__ unsigned pmax(unsigned a, unsigned b) {
    unsigned hi = max(a >> 16, b >> 16);
    unsigned lo = max(a & 0xFFFFu, b & 0xFFFFu);
    return (hi << 16) | lo;
}

// ---------------------------------------------------------------------------
__global__ void k_pack2(const float* __restrict__ W1, const float* __restrict__ b1,
                        const float* __restrict__ W2, unsigned* __restrict__ ws) {
    int t = threadIdx.x;                    // 512 threads
    float* w1p = reinterpret_cast<float*>(ws);
    if (t < 256) {
        float4 v;
        v.x = W1[t * 3 + 0];
        v.y = W1[t * 3 + 1];
        v.z = W1[t * 3 + 2];
        v.w = b1[t];
        reinterpret_cast<float4*>(w1p)[t] = v;
    }
    // W2 B fragments with k-map c(kt,j,g) = kt*32 + (j>>2)*16 + 4g + (j&3):
    // word0: j=0,1 -> base+0, base+1 ; word1: j=2,3 -> base+2,+3
    // word2: j=4,5 -> base+16,+17   ; word3: j=6,7 -> base+18,+19
    int kt = t >> 6, l = t & 63;
    int g = (l >> 4), o = l & 15;
    const float* wr = W2 + o * CDIM + kt * 32 + 4 * g;   // base
    uint4 q;
    q.x = pkbf16(wr[0],  wr[1]);
    q.y = pkbf16(wr[2],  wr[3]);
    q.z = pkbf16(wr[16], wr[17]);
    q.w = pkbf16(wr[18], wr[19]);
    reinterpret_cast<uint4*>(ws + 1024)[t] = q;
}

// ---------------------------------------------------------------------------
// per-word (2x bf16-mapped u16) max via CAS; low contention expected
__device__ __forceinline__ void casmax(unsigned* addr, unsigned wv) {
    unsigned cur = *addr;
    while (true) {
        unsigned nv = pmax(cur, wv);
        if (nv == cur) return;
        unsigned prev = atomicCAS(addr, cur, nv);
        if (prev == cur) return;
        cur = prev;
    }
}

__device__ __forceinline__ bf16x8 mk_frag(unsigned w0, unsigned w1) {
    u32x4 u = {w0, w1, 0u, 0u};
    return __builtin_bit_cast(bf16x8, u);
}

// ---------------------------------------------------------------------------
// MFMA scatter: block (k, b). 8 waves (2/SIMD); each wave does 2x 16-point
// M-tiles per iteration. BOTH layers on MFMA:
//   L1: D[ch16][pt16] = W1(A-frag, regs) * x(B-frag)   [K=4 of 32 used]
//   L2: D[pt16][och16] = h(A-frag, from L1 in-lane) * W2(B-frag, regs)
// k<->c bijection c(kt,j,g)=kt*32+(j>>2)*16+4g+(j&3) makes L1 output rows
// (ch = cg*16+4g+r) exactly the L2 A-slots -> zero cross-lane traffic.
// In-loop LDS = epilogue shuffles + casmax only. W1/W2 fragments in VGPRs.
__global__ __launch_bounds__(TPB, 1)
void k_scatter_mfma(const float* __restrict__ xin,
                    const unsigned* __restrict__ ws,
                    const float* __restrict__ b2,
                    unsigned* __restrict__ slabs,
                    int nper, int chunk) {
    __shared__ unsigned cm[SLAB_WORDS];      // 128 KiB
    const int kblk = blockIdx.x, b = blockIdx.z;
    const int tid = threadIdx.x;
    const int l = tid & 63, wv = tid >> 6;   // lane, wave (0..7)
    const int g = l >> 4;                    // lane group 0..3
    const bool g0 = (g == 0);

    {   // vectorized sentinel init: 8192 uint4
        u32x4 s = {SENTPK, SENTPK, SENTPK, SENTPK};
        u32x4* cm4 = reinterpret_cast<u32x4*>(cm);
        for (int i = tid; i < SLAB_WORDS / 4; i += TPB) cm4[i] = s;
    }

    // ---- W1 A-fragments (16 channel groups) into registers ----
    // lane l supplies A[m=l&15][k=g*8+j]; only g==0 lanes carry (w1x,w1y,w1z,b1)
    bf16x8 w1f[16];
    {
        const float4* w1p = reinterpret_cast<const float4*>(ws);
#pragma unroll
        for (int cg = 0; cg < 16; ++cg) {
            float4 w = w1p[cg * 16 + (l & 15)];
            unsigned a0 = g0 ? pkbf16(w.x, w.y) : 0u;
            unsigned a1 = g0 ? pkbf16(w.z, w.w) : 0u;
            w1f[cg] = mk_frag(a0, a1);
        }
    }
    // ---- W2 B-fragments into registers ----
    bf16x8 w2f[8];
#pragma unroll
    for (int kt = 0; kt < 8; ++kt) {
        u32x4 q = reinterpret_cast<const u32x4*>(ws + 1024)[kt * 64 + l];
        w2f[kt] = __builtin_bit_cast(bf16x8, q);
    }
    float b2v = b2[l & 15];
    __syncthreads();

    const int p0 = kblk * chunk;
    const int p1 = min(p0 + chunk, nper);
    const float* xb = xin + (size_t)b * nper * 3;
    const f32x4 z4 = {0.f, 0.f, 0.f, 0.f};

    // prefetched x for current iteration
    float ax, ay, az, bx, by, bz;
    {
        int pa = min(p0 + wv * 32 + (l & 15), nper - 1);
        int pb = min(p0 + wv * 32 + 16 + (l & 15), nper - 1);
        ax = xb[pa * 3 + 0]; ay = xb[pa * 3 + 1]; az = xb[pa * 3 + 2];
        bx = xb[pb * 3 + 0]; by = xb[pb * 3 + 1]; bz = xb[pb * 3 + 2];
    }

    for (int gb = p0 + wv * 32; gb < p1; gb += (TPB / 64) * 32) {
        // ---- issue next-iter x loads early (clamped, branchless) ----
        int ngb = gb + (TPB / 64) * 32;
        int npa = min(ngb + (l & 15), nper - 1);
        int npb = min(ngb + 16 + (l & 15), nper - 1);
        float nax = xb[npa * 3 + 0], nay = xb[npa * 3 + 1], naz = xb[npa * 3 + 2];
        float nbx = xb[npb * 3 + 0], nby = xb[npb * 3 + 1], nbz = xb[npb * 3 + 2];

        int cellA = ((min(max((int)floorf(ax), 0), 15) << 8) |
                     (min(max((int)floorf(ay), 0), 15) << 4) |
                      min(max((int)floorf(az), 0), 15));
        int cellB = ((min(max((int)floorf(bx), 0), 15) << 8) |
                     (min(max((int)floorf(by), 0), 15) << 4) |
                      min(max((int)floorf(bz), 0), 15));

        // ---- x B-fragments: lane's own point, (x,y,z,1) in k=0..3 (g==0) ----
        bf16x8 bxA = mk_frag(g0 ? pkbf16(ax, ay) : 0u, g0 ? pkbf16(az, 1.0f) : 0u);
        bf16x8 bxB = mk_frag(g0 ? pkbf16(bx, by) : 0u, g0 ? pkbf16(bz, 1.0f) : 0u);

        f32x4 accA = z4, accB = z4;
#pragma unroll
        for (int kt = 0; kt < 8; ++kt) {
            // L1: two channel groups per kt, both tiles (4 MFMAs)
            f32x4 hA0 = __builtin_amdgcn_mfma_f32_16x16x32_bf16(w1f[2*kt],   bxA, z4, 0, 0, 0);
            f32x4 hA1 = __builtin_amdgcn_mfma_f32_16x16x32_bf16(w1f[2*kt+1], bxA, z4, 0, 0, 0);
            f32x4 hB0 = __builtin_amdgcn_mfma_f32_16x16x32_bf16(w1f[2*kt],   bxB, z4, 0, 0, 0);
            f32x4 hB1 = __builtin_amdgcn_mfma_f32_16x16x32_bf16(w1f[2*kt+1], bxB, z4, 0, 0, 0);
            // relu + pack into L2 A-fragments (in-lane by c-map construction)
            u32x4 uaA, uaB;
            uaA[0] = pkbf16(fmaxf(hA0[0],0.f), fmaxf(hA0[1],0.f));
            uaA[1] = pkbf16(fmaxf(hA0[2],0.f), fmaxf(hA0[3],0.f));
            uaA[2] = pkbf16(fmaxf(hA1[0],0.f), fmaxf(hA1[1],0.f));
            uaA[3] = pkbf16(fmaxf(hA1[2],0.f), fmaxf(hA1[3],0.f));
            uaB[0] = pkbf16(fmaxf(hB0[0],0.f), fmaxf(hB0[1],0.f));
            uaB[1] = pkbf16(fmaxf(hB0[2],0.f), fmaxf(hB0[3],0.f));
            uaB[2] = pkbf16(fmaxf(hB1[0],0.f), fmaxf(hB1[1],0.f));
            uaB[3] = pkbf16(fmaxf(hB1[2],0.f), fmaxf(hB1[3],0.f));
            // L2 accumulate
            accA = __builtin_amdgcn_mfma_f32_16x16x32_bf16(
                       __builtin_bit_cast(bf16x8, uaA), w2f[kt], accA, 0, 0, 0);
            accB = __builtin_amdgcn_mfma_f32_16x16x32_bf16(
                       __builtin_bit_cast(bf16x8, uaB), w2f[kt], accB, 0, 0, 0);
        }

        // ---- epilogue per tile: +b2, bf16 cvt_pk, packed map, CAS into cm --
#pragma unroll
        for (int tile = 0; tile < 2; ++tile) {
            f32x4 acc = tile ? accB : accA;
            int cell16 = tile ? cellB : cellA;
            int gbase = gb + tile * 16;

            unsigned pk01 = mpk(pkbf16(acc[0] + b2v, acc[1] + b2v));
            unsigned pk23 = mpk(pkbf16(acc[2] + b2v, acc[3] + b2v));
            unsigned q01 = __shfl_xor(pk01, 1);
            unsigned q23 = __shfl_xor(pk23, 1);
            int half = l & 1;
            unsigned aown = half ? pk23 : pk01;
            unsigned apar = half ? q23 : q01;
            unsigned losrc = half ? apar : aown;   // even channel -> lo
            unsigned hisrc = half ? aown : apar;   // odd channel  -> hi
            unsigned wA = (losrc & 0xFFFFu) | ((hisrc & 0xFFFFu) << 16);
            unsigned wB = (losrc >> 16) | (hisrc & 0xFFFF0000u);
            int r0 = g * 4 + half * 2;
            int cA = __shfl(cell16, r0);
            int cB = __shfl(cell16, r0 + 1);
            unsigned op = (l >> 1) & 7;
            if (gbase + r0 < p1)     casmax(&cm[cA * 8 + op], wA);
            if (gbase + r0 + 1 < p1) casmax(&cm[cB * 8 + op], wB);
        }

        ax = nax; ay = nay; az = naz;
        bx = nbx; by = nby; bz = nbz;
    }
    __syncthreads();

    // flush slab (flat copy; layout preserved)
    unsigned* dst = slabs + (size_t)(kblk * BATCH + b) * SLAB_WORDS;
    uint4* d4 = reinterpret_cast<uint4*>(dst);
    const uint4* s4 = reinterpret_cast<const uint4*>(cm);
    for (int i = tid; i < SLAB_WORDS / 4; i += TPB) d4[i] = s4[i];
}

// ---------------------------------------------------------------------------
// reduce K slabs -> out interior. thread = (b, cell); reads 8 contiguous
// words per slab (2x uint4), writes 16 channels.
__global__ __launch_bounds__(256)
void k_reduce3(const unsigned* __restrict__ slabs, float* __restrict__ out, int K) {
    int t = blockIdx.x * 256 + threadIdx.x;
    if (t >= BATCH * NCELL) return;
    int cell = t & (NCELL - 1), b = t >> 12;

    unsigned m[8];
#pragma unroll
    for (int i = 0; i < 8; ++i) m[i] = SENTPK;

    for (int k = 0; k < K; ++k) {
        const uint4* s = reinterpret_cast<const uint4*>(
            slabs + (size_t)(k * BATCH + b) * SLAB_WORDS + (size_t)cell * 8);
        uint4 a = s[0], c = s[1];
        m[0] = pmax(m[0], a.x); m[1] = pmax(m[1], a.y);
        m[2] = pmax(m[2], a.z); m[3] = pmax(m[3], a.w);
        m[4] = pmax(m[4], c.x); m[5] = pmax(m[5], c.y);
        m[6] = pmax(m[6], c.z); m[7] = pmax(m[7], c.w);
    }

    int ix = cell >> 8, iy = (cell >> 4) & 15, iz = cell & 15;
    size_t obase = ((size_t)b * ODIM) * PADV + ((ix * PADW + iy) * PADW + iz);
#pragma unroll
    for (int op = 0; op < 8; ++op) {
        unsigned lo = m[op] & 0xFFFFu, hi = m[op] >> 16;
        out[obase + (size_t)(2 * op)     * PADV] = (lo == SENT16) ? 0.0f : unmap16(lo);
        out[obase + (size_t)(2 * op + 1) * PADV] = (hi == SENT16) ? 0.0f : unmap16(hi);
    }
}

// ===========================================================================
// Fallback (round-1): direct global atomics. Used only if ws too small.
__global__ void k_init(unsigned* __restrict__ out, int total) {
    int i = blockIdx.x * blockDim.x + threadIdx.x;
    if (i >= total) return;
    int r = i % PADV;
    int z = r % PADW, y = (r / PADW) % PADW, x = r / (PADW * PADW);
    out[i] = (x < GRID16 && y < GRID16 && z < GRID16) ? 0xFF800000u : 0u;
}
__device__ __forceinline__ void atomicMaxFloat(float* addr, float v) {
    if (v >= 0.0f) atomicMax(reinterpret_cast<int*>(addr), __float_as_int(v));
    else           atomicMin(reinterpret_cast<unsigned*>(addr), __float_as_uint(v));
}
__global__ __launch_bounds__(256)
void k_scatter_glb(const float* __restrict__ xin,
                   const float* __restrict__ W1, const float* __restrict__ b1,
                   const float* __restrict__ W2, const float* __restrict__ b2,
                   float* __restrict__ out, int npts, int nper) {
    int p = blockIdx.x * 256 + threadIdx.x;
    if (p >= npts) return;
    float x0 = xin[p*3+0], x1 = xin[p*3+1], x2 = xin[p*3+2];
    float acc[ODIM];
#pragma unroll
    for (int o = 0; o < ODIM; ++o) acc[o] = b2[o];
#pragma unroll 2
    for (int c = 0; c < CDIM; ++c) {
        float h = fmaf(W1[c*3+0], x0, fmaf(W1[c*3+1], x1, fmaf(W1[c*3+2], x2, b1[c])));
        h = fmaxf(h, 0.0f);
#pragma unroll
        for (int o = 0; o < ODIM; ++o) acc[o] = fmaf(W2[o*CDIM+c], h, acc[o]);
    }
    int ix = min(max((int)floorf(x0), 0), GRID16-1);
    int iy = min(max((int)floorf(x1), 0), GRID16-1);
    int iz = min(max((int)floorf(x2), 0), GRID16-1);
    int b = p / nper;
    size_t base = ((((size_t)b*ODIM)*PADW + ix)*PADW + iy)*PADW + iz;
#pragma unroll
    for (int o = 0; o < ODIM; ++o)
        atomicMaxFloat(out + base + (size_t)o*PADV, acc[o]);
}
__global__ void k_final(unsigned* __restrict__ out, int total) {
    int i = blockIdx.x * blockDim.x + threadIdx.x;
    if (i >= total) return;
    if (out[i] == 0xFF800000u) out[i] = 0u;
}

// ===========================================================================
extern "C" void kernel_launch(void* const* d_in, const int* in_sizes, int n_in,
                              void* d_out, int out_size, void* d_ws, size_t ws_size,
                              hipStream_t stream) {
    const float* x  = (const float*)d_in[0];
    const float* W1 = (const float*)d_in[1];
    const float* b1 = (const float*)d_in[2];
    const float* W2 = (const float*)d_in[3];
    const float* b2 = (const float*)d_in[4];
    float* out = (float*)d_out;

    int npts = in_sizes[0] / 3;          // B*N
    int nper = npts / BATCH;             // N

    size_t ws_words = ws_size / 4;
    int Km = 0;
    if (ws_words > HDR_WORDS) {
        size_t avail = (ws_words - HDR_WORDS) / ((size_t)BATCH * SLAB_WORDS);
        Km = (int)min((size_t)MAXK, avail);
    }

    if (Km >= 1) {
        unsigned* ws = (unsigned*)d_ws;
        k_pack2<<<1, 512, 0, stream>>>(W1, b1, W2, ws);
        (void)hipMemsetAsync(d_out, 0, (size_t)out_size * sizeof(float), stream);

        unsigned* slabs = ws + HDR_WORDS;
        int chunk = (nper + Km - 1) / Km;
        dim3 grid(Km, 1, BATCH);
        k_scatter_mfma<<<grid, TPB, 0, stream>>>(x, ws, b2, slabs, nper, chunk);

        int rt = BATCH * NCELL;
        k_reduce3<<<(rt + 255) / 256, 256, 0, stream>>>(slabs, out, Km);
    } else {
        int total = out_size;
        k_init<<<(total + 255) / 256, 256, 0, stream>>>((unsigned*)out, total);
        int blocks = (npts + 255) / 256;
        k_scatter_glb<<<blocks, 256, 0, stream>>>(x, W1, b1, W2, b2, out, npts, nper);
        k_final<<<(total + 255) / 256, 256, 0, stream>>>((unsigned*)out, total);
    }
}